// Round 6
// baseline (504.553 us; speedup 1.0000x reference)
//
#include <hip/hip_runtime.h>
#include <math.h>

#define NK 2048
#define NT 512
#define NC 32
#define NM 512
#define NBLK 256
#define NCHAIN 32
#define MAGICV 0x13579BDFu

// ws layout (floats):
//   [0..511]      r1        (chain layer-1 output)
//   [512..1023]   r2
//   [1024..1535]  r3
//   [1536..2047]  r4
//   [2048..2559]  g
//   [2560.. ]     flags: 5 arrays of 32 uint32 (viewed as unsigned*)
// Flags are init-free: harness poisons ws to 0xAA bytes; any value != MAGICV
// means "not done", so no zero-init (and no init race) is needed.

__device__ __forceinline__ float eff_w(float w, float m) {
    // tanh(w) * sigmoid(m)  (keep precise libm forms; chain is latency-hidden)
    return tanhf(w) * (1.0f / (1.0f + expf(-m)));
}

__device__ __forceinline__ void set_flag(unsigned* f, int b) {
    // prior plain global stores of this BLOCK are complete at L2 by the
    // preceding __syncthreads (each wave drains vmcnt before s_barrier);
    // agent-scope release makes them visible device-wide (L2 writeback).
    __threadfence();
    __hip_atomic_store(&f[b], MAGICV, __ATOMIC_RELEASE, __HIP_MEMORY_SCOPE_AGENT);
}

__device__ __forceinline__ void wait_flags(unsigned* f, int tid) {
    const int lane = tid & 63;
    for (;;) {
        unsigned v = (lane < NCHAIN)
            ? __hip_atomic_load(&f[lane], __ATOMIC_ACQUIRE, __HIP_MEMORY_SCOPE_AGENT)
            : MAGICV;
        if (__all(v == MAGICV)) break;
        __builtin_amdgcn_s_sleep(2);
    }
    __threadfence();   // acquire fence: subsequent plain loads see remote writes
}

__global__ __launch_bounds__(256) void mega_kernel(
    const float* __restrict__ X,   const float* __restrict__ noise,
    const float* __restrict__ wz1, const float* __restrict__ mz1,
    const float* __restrict__ wz2, const float* __restrict__ mz2,
    const float* __restrict__ wu,  const float* __restrict__ mu,
    const float* __restrict__ wt1, const float* __restrict__ mt1,
    const float* __restrict__ wt2, const float* __restrict__ mt2,
    const float* __restrict__ wt3, const float* __restrict__ mt3,
    const float* __restrict__ wd1, const float* __restrict__ md1,
    const float* __restrict__ wd2, const float* __restrict__ md2,
    const float* __restrict__ wd3, const float* __restrict__ md3,
    float* __restrict__ out, float* __restrict__ ws)
{
    __shared__ float uni[9][NT];      // staged uni_y rows (max 9 k per block)
    __shared__ float rl[NM];          // chain rin staging; later reused as g
    __shared__ float part[16][17];    // chain LDS reduction (pad avoids conflicts)
    __shared__ float W1s[NC * NC];
    __shared__ float W2s[NC];
    __shared__ float vl[NC], ul[NC];
    __shared__ float wred[4];

    const int tid = threadIdx.x;
    const int b   = blockIdx.x;
    float*    rows = ws;                               // 5 x 512 row buffers
    unsigned* flg  = (unsigned*)(ws + 5 * NM);         // 5 x 32 flags

    // ---- k-range assignment (chain blocks start X late -> give them less) ----
    int kstart, nk;
    if (b < NCHAIN) { kstart = 1920 + b * 4; nk = 4; }
    else {
        const int bx = b - NCHAIN;                     // 0..223
        if (bx < 128) { kstart = bx * 9;              nk = 9; }
        else          { kstart = 1152 + (bx-128) * 8; nk = 8; }
    }

    // ================= chain duty (blocks 0..31) =================
    if (b < NCHAIN) {
        const int jj = tid & 15;       // 16 j-columns per block
        const int ig = tid >> 4;       // 16 groups x 32 i-rows
        const int j0 = b * 16;

        // rin = r0 = eff(wd3, md3)
        for (int e = tid; e < NM; e += 256) rl[e] = eff_w(wd3[e], md3[e]);
        __syncthreads();

        const float* Ws[5] = {wd2, wd1, wt3, wt2, wt1};
        const float* Ms[5] = {md2, md1, mt3, mt2, mt1};
        #pragma unroll
        for (int l = 0; l < 5; ++l) {
            const float* __restrict__ w = Ws[l];
            const float* __restrict__ m = Ms[l];
            float acc = 0.f;
            #pragma unroll 4
            for (int s = 0; s < 32; ++s) {
                const int i = ig * 32 + s;
                const size_t off = (size_t)i * NM + j0 + jj;
                acc += rl[i] * eff_w(w[off], m[off]);
            }
            part[jj][ig] = acc;
            __syncthreads();
            if (tid < 16) {
                float ssum = 0.f;
                #pragma unroll
                for (int q = 0; q < 16; ++q) ssum += part[tid][q];
                rows[l * NM + j0 + tid] = ssum;
            }
            __syncthreads();                       // drains the 16 global stores
            if (tid == 0) set_flag(flg + l * NCHAIN, b);
            wait_flags(flg + l * NCHAIN, tid);
            __syncthreads();
            for (int e = tid; e < NM; e += 256) rl[e] = rows[l * NM + e];
            __syncthreads();
        }
        // rl now holds g (restaged again below, harmless)
    }

    // ================= v, u (all blocks; X blocks do this immediately) ======
    for (int e = tid; e < NC * NC; e += 256) W1s[e] = eff_w(wz1[e], mz1[e]);
    if (tid < NC) W2s[tid] = eff_w(wz2[tid], mz2[tid]);
    __syncthreads();
    if (tid < NC) {
        float a = 0.f;
        #pragma unroll
        for (int j = 0; j < NC; ++j) a += W2s[j] * W1s[j * NC + tid];
        vl[tid] = a;                                 // v[c]
        ul[tid] = eff_w(wu[tid], mu[tid]);           // u[c]
    }
    __syncthreads();

    // ================= X streaming: uni[k,t] = X[k,t,:] . v =================
    const int c = (tid * 4) & 31;                    // iteration-invariant
    const float v0 = vl[c], v1 = vl[c + 1], v2 = vl[c + 2], v3 = vl[c + 3];

    for (int kr = 0; kr < nk; ++kr) {
        const int k = kstart + kr;
        const float4* __restrict__ Xk = (const float4*)(X + (size_t)k * (NT * NC));
        #pragma unroll
        for (int it = 0; it < 16; ++it) {
            const float4 x = Xk[tid + it * 256];
            float p = x.x * v0 + x.y * v1 + x.z * v2 + x.w * v3;
            p += __shfl_xor(p, 1);
            p += __shfl_xor(p, 2);
            p += __shfl_xor(p, 4);                   // 8 lanes share one t
            if ((tid & 7) == 0) uni[kr][(tid >> 3) + it * 32] = p;
        }
    }

    // ================= wait for g, stage it =================
    wait_flags(flg + 4 * NCHAIN, tid);               // chain blocks: instant
    __syncthreads();                                 // also covers uni[] writes
    for (int e = tid; e < NM; e += 256) rl[e] = rows[4 * NM + e];   // rl = g
    __syncthreads();

    // ================= epilogue per k =================
    for (int kr = 0; kr < nk; ++kr) {
        const int k = kstart + kr;
        // delta = uni[k,:] . g
        float d = uni[kr][tid] * rl[tid] + uni[kr][tid + 256] * rl[tid + 256];
        #pragma unroll
        for (int off = 32; off > 0; off >>= 1) d += __shfl_xor(d, off);
        if ((tid & 63) == 0) wred[tid >> 6] = d;
        __syncthreads();
        if (tid < 64) {
            const float delta = wred[0] + wred[1] + wred[2] + wred[3];
            const int cc = tid & 31;
            const float lx = X[(size_t)k * (NT * NC) + (size_t)(NT - 1) * NC + cc];
            float s = lx;
            s += __shfl_xor(s, 1);
            s += __shfl_xor(s, 2);
            s += __shfl_xor(s, 4);
            s += __shfl_xor(s, 8);
            s += __shfl_xor(s, 16);                  // sum over the 32-group
            if (tid < 32) {
                const float bse = lx - s * (1.0f / NC);
                const float n = noise[k * NC + cc];
                out[k * NC + cc] = delta * ul[cc] + bse * (1.0f + 0.001f * n);
            }
        }
        __syncthreads();                             // wred reused next kr
    }
}

extern "C" void kernel_launch(void* const* d_in, const int* in_sizes, int n_in,
                              void* d_out, int out_size, void* d_ws, size_t ws_size,
                              hipStream_t stream)
{
    const float* X     = (const float*)d_in[0];
    const float* noise = (const float*)d_in[1];
    const float* wz1   = (const float*)d_in[2];
    const float* mz1   = (const float*)d_in[3];
    const float* wz2   = (const float*)d_in[4];
    const float* mz2   = (const float*)d_in[5];
    const float* wu    = (const float*)d_in[6];
    const float* mu    = (const float*)d_in[7];
    const float* wt1   = (const float*)d_in[8];
    const float* mt1   = (const float*)d_in[9];
    const float* wt2   = (const float*)d_in[10];
    const float* mt2   = (const float*)d_in[11];
    const float* wt3   = (const float*)d_in[12];
    const float* mt3   = (const float*)d_in[13];
    const float* wd1   = (const float*)d_in[14];
    const float* md1   = (const float*)d_in[15];
    const float* wd2   = (const float*)d_in[16];
    const float* md2   = (const float*)d_in[17];
    const float* wd3   = (const float*)d_in[18];
    const float* md3   = (const float*)d_in[19];
    float* out = (float*)d_out;
    float* ws  = (float*)d_ws;

    mega_kernel<<<NBLK, 256, 0, stream>>>(
        X, noise, wz1, mz1, wz2, mz2, wu, mu,
        wt1, mt1, wt2, mt2, wt3, mt3,
        wd1, md1, wd2, md2, wd3, md3, out, ws);
}

// Round 7
// 301.071 us; speedup vs baseline: 1.6759x; 1.6759x over previous
//
#include <hip/hip_runtime.h>
#include <math.h>

#define NK 2048
#define NT 512
#define NC 32
#define NM 512
#define NCHAIN 32
#define MAGICV 0x13579BDFu

// ws float layout:
//   [UNI_OFF .. +NK*NT)          uni[k][t]               (4 MB)
//   [P_OFF   .. +5*32*512)       chain partials P[l][b][j]
//   [FLG_OFF .. +5*32 u32)       per-(layer,block) done flags (init-free:
//                                harness poisons ws to 0xAA; MAGICV != poison)
#define UNI_OFF 0
#define P_OFF   (NK * NT)
#define FLG_OFF (P_OFF + 5 * NCHAIN * NM)

__device__ __forceinline__ float eff_w(float w, float m) {
    // tanh(w) * sigmoid(m)
    return tanhf(w) * (1.0f / (1.0f + expf(-m)));
}

// K2: blocks 0..31 compute the 5-layer g-chain (partials in ws, relaxed-spin
// sync among the 32 blocks only); blocks 32..2079 each compute uni[k,:] for
// one k and exit. No uni block ever spins.
__global__ __launch_bounds__(256) void uni_chain_kernel(
    const float* __restrict__ X,
    const float* __restrict__ wz1, const float* __restrict__ mz1,
    const float* __restrict__ wz2, const float* __restrict__ mz2,
    const float* __restrict__ wt1, const float* __restrict__ mt1,
    const float* __restrict__ wt2, const float* __restrict__ mt2,
    const float* __restrict__ wt3, const float* __restrict__ mt3,
    const float* __restrict__ wd1, const float* __restrict__ md1,
    const float* __restrict__ wd2, const float* __restrict__ md2,
    const float* __restrict__ wd3, const float* __restrict__ md3,
    float* __restrict__ ws)
{
    __shared__ float W1s[NC * NC];
    __shared__ float W2s[NC];
    __shared__ float vl[NC];
    __shared__ float unirow[NT];
    __shared__ float rl[NM];
    __shared__ float4 part[2][128];

    const int tid = threadIdx.x;
    const int b   = blockIdx.x;
    float*    P   = ws + P_OFF;
    unsigned* flg = (unsigned*)(ws + FLG_OFF);

    if (b < NCHAIN) {
        // ---------- chain duty ----------
        for (int e = tid; e < NM; e += 256) rl[e] = eff_w(wd3[e], md3[e]);
        __syncthreads();

        const float* Ws[5] = {wd2, wd1, wt3, wt2, wt1};
        const float* Ms[5] = {md2, md1, mt3, mt2, mt1};
        const int j4   = (tid & 127) * 4;   // this thread's 4 j-columns
        const int half = tid >> 7;          // row half: 0 -> rows 0..7, 1 -> 8..15

        #pragma unroll
        for (int l = 0; l < 5; ++l) {
            const float* __restrict__ w = Ws[l];
            const float* __restrict__ m = Ms[l];
            float ax = 0.f, ay = 0.f, az = 0.f, aw = 0.f;
            #pragma unroll
            for (int s = 0; s < 8; ++s) {
                const int i = b * 16 + half * 8 + s;        // coalesced row-band
                const float ri = rl[i];
                const float4 wv = *(const float4*)(w + (size_t)i * NM + j4);
                const float4 mv = *(const float4*)(m + (size_t)i * NM + j4);
                ax += ri * eff_w(wv.x, mv.x);
                ay += ri * eff_w(wv.y, mv.y);
                az += ri * eff_w(wv.z, mv.z);
                aw += ri * eff_w(wv.w, mv.w);
            }
            part[half][tid & 127] = make_float4(ax, ay, az, aw);
            __syncthreads();

            float* Pl = P + (size_t)l * NCHAIN * NM;
            if (tid < 128) {
                const float4 a = part[0][tid], c = part[1][tid];
                *(float4*)(Pl + b * NM + tid * 4) =
                    make_float4(a.x + c.x, a.y + c.y, a.z + c.z, a.w + c.w);
            }
            __syncthreads();   // waves drain vmcnt before s_barrier -> stores done

            if (l < 4) {
                unsigned* fl = flg + l * NCHAIN;
                if (tid == 0) {
                    __threadfence();   // release: push partials to coherence point
                    __hip_atomic_store(&fl[b], MAGICV, __ATOMIC_RELEASE,
                                       __HIP_MEMORY_SCOPE_AGENT);
                }
                if (tid < 64) {
                    // RELAXED atomic loads: read the coherence point without
                    // per-iteration cache invalidation (the R6 storm).
                    for (;;) {
                        unsigned vv = (tid < NCHAIN)
                            ? __hip_atomic_load(&fl[tid], __ATOMIC_RELAXED,
                                                __HIP_MEMORY_SCOPE_AGENT)
                            : MAGICV;
                        if (__all(vv == MAGICV)) break;
                        __builtin_amdgcn_s_sleep(8);
                    }
                }
                __syncthreads();
                __threadfence();       // acquire: invalidate stale lines once

                float s0 = 0.f, s1 = 0.f;
                for (int bb = 0; bb < NCHAIN; ++bb) {
                    s0 += Pl[bb * NM + tid];
                    s1 += Pl[bb * NM + tid + 256];
                }
                rl[tid] = s0; rl[tid + 256] = s1;
                __syncthreads();
            }
        }
        return;   // layer-4 partials are summed by the epilogue kernel
    }

    // ---------- uni duty: one k per block ----------
    const int k = b - NCHAIN;
    for (int e = tid; e < NC * NC; e += 256) W1s[e] = eff_w(wz1[e], mz1[e]);
    if (tid < NC) W2s[tid] = eff_w(wz2[tid], mz2[tid]);
    __syncthreads();
    if (tid < NC) {
        float a = 0.f;
        #pragma unroll
        for (int j = 0; j < NC; ++j) a += W2s[j] * W1s[j * NC + tid];
        vl[tid] = a;                    // v[c]
    }
    __syncthreads();

    const int c = (tid * 4) & 31;       // iteration-invariant v slice
    const float v0 = vl[c], v1 = vl[c + 1], v2 = vl[c + 2], v3 = vl[c + 3];
    const float4* __restrict__ Xk = (const float4*)(X + (size_t)k * (NT * NC));
    #pragma unroll
    for (int it = 0; it < 16; ++it) {
        const float4 x = Xk[tid + it * 256];
        float p = x.x * v0 + x.y * v1 + x.z * v2 + x.w * v3;
        p += __shfl_xor(p, 1);
        p += __shfl_xor(p, 2);
        p += __shfl_xor(p, 4);          // 8 lanes share one t
        if ((tid & 7) == 0) unirow[(tid >> 3) + it * 32] = p;
    }
    __syncthreads();
    if (tid < 128)
        *(float4*)(ws + UNI_OFF + (size_t)k * NT + tid * 4) =
            *(const float4*)(unirow + tid * 4);
}

// K3: 128 blocks x 256. Sum layer-4 g-partials, then per-k delta + baseline.
__global__ __launch_bounds__(256) void epilogue_kernel(
    const float* __restrict__ X, const float* __restrict__ noise,
    const float* __restrict__ wu, const float* __restrict__ mu,
    float* __restrict__ out, const float* __restrict__ ws)
{
    __shared__ float gl[NM];
    __shared__ float ul[NC];
    __shared__ float wred[4];
    const int tid = threadIdx.x;

    const float* P4 = ws + P_OFF + (size_t)4 * NCHAIN * NM;
    float s0 = 0.f, s1 = 0.f;
    for (int bb = 0; bb < NCHAIN; ++bb) {
        s0 += P4[bb * NM + tid];
        s1 += P4[bb * NM + tid + 256];
    }
    gl[tid] = s0; gl[tid + 256] = s1;
    if (tid < NC) ul[tid] = eff_w(wu[tid], mu[tid]);
    __syncthreads();

    for (int kr = 0; kr < 16; ++kr) {
        const int k = blockIdx.x * 16 + kr;
        const float* uk = ws + UNI_OFF + (size_t)k * NT;
        float d = uk[tid] * gl[tid] + uk[tid + 256] * gl[tid + 256];
        #pragma unroll
        for (int off = 32; off > 0; off >>= 1) d += __shfl_xor(d, off);
        if ((tid & 63) == 0) wred[tid >> 6] = d;
        __syncthreads();
        if (tid < 64) {
            const float delta = wred[0] + wred[1] + wred[2] + wred[3];
            const int cc = tid & 31;
            const float lx = X[(size_t)k * (NT * NC) + (size_t)(NT - 1) * NC + cc];
            float s = lx;
            s += __shfl_xor(s, 1);
            s += __shfl_xor(s, 2);
            s += __shfl_xor(s, 4);
            s += __shfl_xor(s, 8);
            s += __shfl_xor(s, 16);
            if (tid < 32) {
                const float bse = lx - s * (1.0f / NC);
                const float n = noise[k * NC + cc];
                out[k * NC + cc] = delta * ul[cc] + bse * (1.0f + 0.001f * n);
            }
        }
        __syncthreads();   // wred reused next kr
    }
}

extern "C" void kernel_launch(void* const* d_in, const int* in_sizes, int n_in,
                              void* d_out, int out_size, void* d_ws, size_t ws_size,
                              hipStream_t stream)
{
    const float* X     = (const float*)d_in[0];
    const float* noise = (const float*)d_in[1];
    const float* wz1   = (const float*)d_in[2];
    const float* mz1   = (const float*)d_in[3];
    const float* wz2   = (const float*)d_in[4];
    const float* mz2   = (const float*)d_in[5];
    const float* wu    = (const float*)d_in[6];
    const float* mu    = (const float*)d_in[7];
    const float* wt1   = (const float*)d_in[8];
    const float* mt1   = (const float*)d_in[9];
    const float* wt2   = (const float*)d_in[10];
    const float* mt2   = (const float*)d_in[11];
    const float* wt3   = (const float*)d_in[12];
    const float* mt3   = (const float*)d_in[13];
    const float* wd1   = (const float*)d_in[14];
    const float* md1   = (const float*)d_in[15];
    const float* wd2   = (const float*)d_in[16];
    const float* md2   = (const float*)d_in[17];
    const float* wd3   = (const float*)d_in[18];
    const float* md3   = (const float*)d_in[19];
    float* out = (float*)d_out;
    float* ws  = (float*)d_ws;

    uni_chain_kernel<<<NK + NCHAIN, 256, 0, stream>>>(
        X, wz1, mz1, wz2, mz2,
        wt1, mt1, wt2, mt2, wt3, mt3,
        wd1, md1, wd2, md2, wd3, md3, ws);
    epilogue_kernel<<<NK / 16, 256, 0, stream>>>(X, noise, wu, mu, out, ws);
}